// Round 1
// baseline (702.565 us; speedup 1.0000x reference)
//
#include <hip/hip_runtime.h>
#include <cmath>

#define N_TOK 8192
#define C_DIM 768
#define H_DIM 3072
#define NEXP  8
#define PADCAP 17408      // 2*N_TOK + NEXP*128
#define MAXMT  136        // PADCAP/128

typedef short short8 __attribute__((ext_vector_type(8)));
typedef float f32x4  __attribute__((ext_vector_type(4)));

// fp32 -> bf16 round-to-nearest-even (finite inputs only)
__device__ __forceinline__ unsigned short f2b(float f) {
  unsigned int u = __float_as_uint(f);
  u += 0x7fffu + ((u >> 16) & 1u);
  return (unsigned short)(u >> 16);
}

// ---------------- gating: fp64 scores, top-2, softmax, counts ----------------
__global__ __launch_bounds__(256) void gate_kernel(
    const float* __restrict__ x, const float* __restrict__ gw,
    const float* __restrict__ gb, int* __restrict__ counts,
    int* __restrict__ tok_e, int* __restrict__ tok_r, float* __restrict__ tok_w) {
  __shared__ float gwl[NEXP * C_DIM];
  __shared__ double red[256][NEXP];
  int tid = threadIdx.x;
  const float4* gw4 = (const float4*)gw;
  float4* gl4 = (float4*)gwl;
  for (int i = tid; i < NEXP * C_DIM / 4; i += 256) gl4[i] = gw4[i];
  __syncthreads();
  int tl = tid & 63;   // token within block
  int kc = tid >> 6;   // k-chunk 0..3 (192 each)
  int t = blockIdx.x * 64 + tl;
  double acc[NEXP];
#pragma unroll
  for (int e = 0; e < NEXP; e++) acc[e] = 0.0;
  const float* xr = x + (size_t)t * C_DIM;
  for (int k = kc * 192; k < kc * 192 + 192; k++) {
    double xv = (double)xr[k];
#pragma unroll
    for (int e = 0; e < NEXP; e++) acc[e] += xv * (double)gwl[e * C_DIM + k];
  }
#pragma unroll
  for (int e = 0; e < NEXP; e++) red[tid][e] = acc[e];
  __syncthreads();
  if (tid < 64) {
    double s[NEXP];
#pragma unroll
    for (int e = 0; e < NEXP; e++)
      s[e] = (double)gb[e] + red[tid][e] + red[tid + 64][e] + red[tid + 128][e] + red[tid + 192][e];
    // top-2, ties -> lower index first (matches jax.lax.top_k)
    double best = s[0], sec = -1e300; int bi = 0, si = -1;
#pragma unroll
    for (int e = 1; e < NEXP; e++) {
      if (s[e] > best)      { sec = best; si = bi; best = s[e]; bi = e; }
      else if (s[e] > sec)  { sec = s[e]; si = e; }
    }
    double ex = exp(sec - best);
    double den = 1.0 + ex;
    tok_e[2 * t] = bi;  tok_e[2 * t + 1] = si;
    tok_w[2 * t] = (float)(1.0 / den);  tok_w[2 * t + 1] = (float)(ex / den);
    tok_r[2 * t]     = atomicAdd(&counts[bi], 1);
    tok_r[2 * t + 1] = atomicAdd(&counts[si], 1);
  }
}

// ---------------- padded offsets (segments rounded up to 128 rows) ----------
__global__ void offsets_kernel(const int* __restrict__ counts, int* __restrict__ po) {
  if (threadIdx.x == 0 && blockIdx.x == 0) {
    int s = 0;
    for (int e = 0; e < NEXP; e++) { po[e] = s; s += (counts[e] + 127) & ~127; }
    po[NEXP] = s;
  }
}

// ---------------- scatter token ids + gate weights into permuted order ------
__global__ __launch_bounds__(256) void scatter_kernel(
    const int* __restrict__ tok_e, const int* __restrict__ tok_r,
    const float* __restrict__ tok_w, const int* __restrict__ po,
    int* __restrict__ perm_t, float* __restrict__ perm_w) {
  int t = blockIdx.x * 256 + threadIdx.x;
#pragma unroll
  for (int k = 0; k < 2; k++) {
    int e = tok_e[2 * t + k];
    int pos = po[e] + tok_r[2 * t + k];
    perm_t[pos] = t;
    perm_w[pos] = tok_w[2 * t + k];
  }
}

// ---------------- gather x rows into permuted bf16 matrix -------------------
__global__ __launch_bounds__(256) void gather_kernel(
    const float* __restrict__ x, const int* __restrict__ po,
    const int* __restrict__ perm_t, unsigned short* __restrict__ xg) {
  int row = blockIdx.x * 4 + (threadIdx.x >> 6);
  if (row >= po[NEXP]) return;
  int l = threadIdx.x & 63;
  int t = perm_t[row];
  const float4* src = (const float4*)(x + (size_t)t * C_DIM);
  ushort4* dst = (ushort4*)(xg + (size_t)row * C_DIM);
#pragma unroll
  for (int j = 0; j < 3; j++) {
    float4 v = src[l + j * 64];
    ushort4 o; o.x = f2b(v.x); o.y = f2b(v.y); o.z = f2b(v.z); o.w = f2b(v.w);
    dst[l + j * 64] = o;
  }
}

// ---------------- fp32 -> bf16 weight conversion ----------------------------
__global__ __launch_bounds__(256) void wconv_kernel(
    const float* __restrict__ wfc, const float* __restrict__ wproj,
    unsigned short* __restrict__ wfcb, unsigned short* __restrict__ wpjb) {
  const int n4 = NEXP * H_DIM * C_DIM / 4;
  int stride = gridDim.x * blockDim.x;
  for (int i = blockIdx.x * blockDim.x + threadIdx.x; i < 2 * n4; i += stride) {
    const float4* s; ushort4* d; int j;
    if (i < n4) { s = (const float4*)wfc;   d = (ushort4*)wfcb; j = i; }
    else        { s = (const float4*)wproj; d = (ushort4*)wpjb; j = i - n4; }
    float4 v = s[j];
    ushort4 o; o.x = f2b(v.x); o.y = f2b(v.y); o.z = f2b(v.z); o.w = f2b(v.w);
    d[j] = o;
  }
}

// ---------------- shared 128x128xK bf16 MFMA core (m97 structure) -----------
// A pre-offset to (row0,0), lda elems; B pre-offset to (n0,0) row-major [n][k].
__device__ __forceinline__ void gemm_core(
    const unsigned short* A, int lda, const unsigned short* B, int ldb, int K,
    unsigned short* lA, unsigned short* lB, int tid, f32x4 acc[4][4]) {
  int w = tid >> 6, l = tid & 63;
  int wm = (w >> 1) * 64, wn = (w & 1) * 64;
  int lrow_a = wm + (l & 15);
  int lrow_b = wn + (l & 15);
  int kb = (l >> 4) * 16;   // byte offset within 64-byte LDS row
  for (int k0 = 0; k0 < K; k0 += 32) {
#pragma unroll
    for (int i = 0; i < 2; i++) {
      int t2 = tid + i * 256;
      int r = t2 >> 2, cb = (t2 & 3) * 16;
      const char* ga  = (const char*)(A + (size_t)r * lda + k0) + cb;
      const char* gbp = (const char*)(B + (size_t)r * ldb + k0) + cb;
      char* la = (char*)lA + i * 4096 + w * 1024;   // wave-uniform base + lane*16
      char* lb = (char*)lB + i * 4096 + w * 1024;
      __builtin_amdgcn_global_load_lds((const __attribute__((address_space(1))) void*)ga,
                                       (__attribute__((address_space(3))) void*)la, 16, 0, 0);
      __builtin_amdgcn_global_load_lds((const __attribute__((address_space(1))) void*)gbp,
                                       (__attribute__((address_space(3))) void*)lb, 16, 0, 0);
    }
    __syncthreads();   // drains vmcnt -> LDS tiles valid
    short8 af[4], bfr[4];
#pragma unroll
    for (int mi = 0; mi < 4; mi++)
      af[mi] = *(const short8*)((const char*)lA + (lrow_a + mi * 16) * 64 + kb);
#pragma unroll
    for (int ni = 0; ni < 4; ni++)
      bfr[ni] = *(const short8*)((const char*)lB + (lrow_b + ni * 16) * 64 + kb);
#pragma unroll
    for (int mi = 0; mi < 4; mi++) {
#pragma unroll
      for (int ni = 0; ni < 4; ni++)
        acc[mi][ni] = __builtin_amdgcn_mfma_f32_16x16x32_bf16(af[mi], bfr[ni], acc[mi][ni], 0, 0, 0);
    }
    __syncthreads();   // all waves done reading before next overwrite
  }
}

// ---------------- FC1: h = gelu(xg @ w_fc^T + b_fc), bf16 out ---------------
__global__ __launch_bounds__(256) void fc1_kernel(
    const unsigned short* __restrict__ xg, const unsigned short* __restrict__ wfcb,
    const float* __restrict__ bfc, const int* __restrict__ po,
    unsigned short* __restrict__ h) {
  __shared__ unsigned short lA[128 * 32];
  __shared__ unsigned short lB[128 * 32];
  int row0 = blockIdx.y * 128;
  if (row0 >= po[NEXP]) return;
  int e = 0;
#pragma unroll
  for (int i = 1; i < NEXP; i++) if (row0 >= po[i]) e = i;
  int n0 = blockIdx.x * 128;
  int tid = threadIdx.x;
  f32x4 acc[4][4];
#pragma unroll
  for (int mi = 0; mi < 4; mi++)
#pragma unroll
    for (int ni = 0; ni < 4; ni++) acc[mi][ni] = (f32x4){0.f, 0.f, 0.f, 0.f};
  gemm_core(xg + (size_t)row0 * C_DIM, C_DIM,
            wfcb + (size_t)e * H_DIM * C_DIM + (size_t)n0 * C_DIM, C_DIM, C_DIM,
            lA, lB, tid, acc);
  int w = tid >> 6, l = tid & 63;
  int wm = (w >> 1) * 64, wn = (w & 1) * 64;
  const float* bias = bfc + (size_t)e * H_DIM;
#pragma unroll
  for (int ni = 0; ni < 4; ni++) {
    int col = n0 + wn + ni * 16 + (l & 15);
    float bv = bias[col];
#pragma unroll
    for (int mi = 0; mi < 4; mi++) {
#pragma unroll
      for (int r = 0; r < 4; r++) {
        int row = row0 + wm + mi * 16 + (l >> 4) * 4 + r;
        float v = acc[mi][ni][r] + bv;
        float g = 0.5f * v * (1.0f + tanhf(0.7978845608028654f * (v + 0.044715f * v * v * v)));
        h[(size_t)row * H_DIM + col] = f2b(g);
      }
    }
  }
}

// ---------------- FC2: out[token] += w * (h @ w_proj^T + b_proj) ------------
__global__ __launch_bounds__(256) void fc2_kernel(
    const unsigned short* __restrict__ h, const unsigned short* __restrict__ wpjb,
    const float* __restrict__ bproj, const int* __restrict__ po,
    const int* __restrict__ perm_t, const float* __restrict__ perm_w,
    float* __restrict__ out) {
  __shared__ unsigned short lA[128 * 32];
  __shared__ unsigned short lB[128 * 32];
  int row0 = blockIdx.y * 128;
  if (row0 >= po[NEXP]) return;
  int e = 0;
#pragma unroll
  for (int i = 1; i < NEXP; i++) if (row0 >= po[i]) e = i;
  int n0 = blockIdx.x * 128;
  int tid = threadIdx.x;
  f32x4 acc[4][4];
#pragma unroll
  for (int mi = 0; mi < 4; mi++)
#pragma unroll
    for (int ni = 0; ni < 4; ni++) acc[mi][ni] = (f32x4){0.f, 0.f, 0.f, 0.f};
  gemm_core(h + (size_t)row0 * H_DIM, H_DIM,
            wpjb + (size_t)e * C_DIM * H_DIM + (size_t)n0 * H_DIM, H_DIM, H_DIM,
            lA, lB, tid, acc);
  int w = tid >> 6, l = tid & 63;
  int wm = (w >> 1) * 64, wn = (w & 1) * 64;
  const float* bias = bproj + (size_t)e * C_DIM;
#pragma unroll
  for (int mi = 0; mi < 4; mi++) {
#pragma unroll
    for (int r = 0; r < 4; r++) {
      int pos = row0 + wm + mi * 16 + (l >> 4) * 4 + r;
      int tk = perm_t[pos];
      float wgt = perm_w[pos];
      if (wgt != 0.f) {
#pragma unroll
        for (int ni = 0; ni < 4; ni++) {
          int col = n0 + wn + ni * 16 + (l & 15);
          float v = (acc[mi][ni][r] + bias[col]) * wgt;
          atomicAdd(&out[(size_t)tk * C_DIM + col], v);
        }
      }
    }
  }
}

extern "C" void kernel_launch(void* const* d_in, const int* in_sizes, int n_in,
                              void* d_out, int out_size, void* d_ws, size_t ws_size,
                              hipStream_t stream) {
  const float* x     = (const float*)d_in[0];
  const float* gw    = (const float*)d_in[1];
  const float* gb    = (const float*)d_in[2];
  const float* wfc   = (const float*)d_in[3];
  const float* bfc   = (const float*)d_in[4];
  const float* wproj = (const float*)d_in[5];
  const float* bproj = (const float*)d_in[6];
  float* out = (float*)d_out;
  char* ws = (char*)d_ws;

  // ws layout (total ~210 MB)
  int*   counts = (int*)(ws + 0);
  int*   po     = (int*)(ws + 64);
  int*   tok_e  = (int*)(ws + 256);
  int*   tok_r  = (int*)(ws + 256 + 65536);
  float* tok_w  = (float*)(ws + 256 + 131072);
  int*   perm_t = (int*)(ws + 256 + 196608);
  float* perm_w = (float*)(ws + 256 + 196608 + 69632);
  const size_t ROUT_END = 336128;
  unsigned short* xg   = (unsigned short*)(ws + ROUT_END);      // 17408x768 bf16
  unsigned short* wfcb = (unsigned short*)(ws + 27074816);      // 8x3072x768 bf16
  unsigned short* wpjb = (unsigned short*)(ws + 64823552);      // 8x768x3072 bf16
  unsigned short* hbuf = (unsigned short*)(ws + 102572288);     // 17408x3072 bf16

  hipMemsetAsync(ws, 0, ROUT_END, stream);
  hipMemsetAsync(d_out, 0, (size_t)N_TOK * C_DIM * sizeof(float), stream);

  gate_kernel<<<N_TOK / 64, 256, 0, stream>>>(x, gw, gb, counts, tok_e, tok_r, tok_w);
  offsets_kernel<<<1, 64, 0, stream>>>(counts, po);
  scatter_kernel<<<N_TOK / 256, 256, 0, stream>>>(tok_e, tok_r, tok_w, po, perm_t, perm_w);
  gather_kernel<<<PADCAP / 4, 256, 0, stream>>>(x, po, perm_t, xg);
  wconv_kernel<<<2048, 256, 0, stream>>>(wfc, wproj, wfcb, wpjb);
  fc1_kernel<<<dim3(H_DIM / 128, MAXMT), 256, 0, stream>>>(xg, wfcb, bfc, po, hbuf);
  fc2_kernel<<<dim3(C_DIM / 128, MAXMT), 256, 0, stream>>>(hbuf, wpjb, bproj, po, perm_t, perm_w, out);
}